// Round 13
// baseline (938.931 us; speedup 1.0000x reference)
//
#include <hip/hip_runtime.h>
#include <math.h>

typedef unsigned short u16;
typedef _Float16 f16;
typedef __attribute__((ext_vector_type(4))) _Float16 f16x4;
typedef __attribute__((ext_vector_type(8))) _Float16 f16x8;
typedef __attribute__((ext_vector_type(4))) float f32x4;

#define NCELL 225
#define AST   136              // act stride in halves (272 B)
#define NROW  227              // 225 cells + zero row (225) + dump row (226)
#define MAXF  31.75f
#define MAXM  (127.0f/((4.0f/16.0f)*3600.0f/256.0f))
#define DYN_LDS (2*NROW*AST*2) // 123,488 B: bufA | bufB (ping-pong, 1 blk/CU)
#define NT    512              // 8 waves = 2 waves/SIMD -> 256 regs/wave budget

// f16 weight buffer layout (element offsets)
#define W_DCONV 0
#define W_C1    196608
#define W_R01   262144
#define W_R02   278528
#define W_FIN   294912
#define W_F16TOT 303104
// f32 section (float-element offsets from wbuf + W_F16TOT)
#define F_MAPB   0
#define F_DCONVB 128
#define F_C1B    640
#define F_R0B1   1152
#define F_R0B2   1280
#define F_FINB   1408
#define F_PRELU  1472
#define F_MAPW   1536
#define F_TOT    2304

__device__ __forceinline__ float bfu(unsigned h){ union{unsigned i; float f;} v; v.i=h<<16; return v.f; }
__device__ __forceinline__ float rcp_f(float x){ return __builtin_amdgcn_rcpf(x); }
__device__ __forceinline__ float silu_f(float x){ return x*rcp_f(1.f+__expf(-x)); }
__device__ __forceinline__ float tanh_f(float z){ return 1.f - 2.f*rcp_f(__expf(2.f*z)+1.f); }
__device__ __forceinline__ float ldp(const void* p, size_t i, int isf){
  return isf ? ((const float*)p)[i] : bfu(((const u16*)p)[i]);
}
#define MFMA16(A, B, C) __builtin_amdgcn_mfma_f32_16x16x32_f16((A), (B), (C), 0, 0, 0)

__global__ __launch_bounds__(256) void k_prep(
    const void* __restrict__ dconv_w, const void* __restrict__ c1_w,
    const void* __restrict__ r0_w1,  const void* __restrict__ r0_w2,
    const void* __restrict__ fin_w,  const void* __restrict__ map_w,
    const void* __restrict__ map_b,  const void* __restrict__ dconv_b,
    const void* __restrict__ c1_b,   const void* __restrict__ r0_b1,
    const void* __restrict__ r0_b2,  const void* __restrict__ fin_b,
    const void* __restrict__ prelu_w,
    const void* __restrict__ x, f16* __restrict__ wbuf)
{
  __shared__ int sflag;
  if (threadIdx.x < 64) {
    unsigned v = ((const u16*)x)[2*threadIdx.x];
    unsigned long long m = __ballot(v > 0x4000u);
    if (threadIdx.x == 0) sflag = (__popcll(m) > 16) ? 1 : 0;
  }
  __syncthreads();
  const int isf = sflag;
  float* fsec = (float*)(wbuf + W_F16TOT);
  const int NTOT = W_F16TOT + F_TOT;
  for (int i = blockIdx.x*256 + threadIdx.x; i < NTOT; i += gridDim.x*256) {
    if (i < W_F16TOT) {
      float v; int j = i;
      if (j < 196608)                 v = ldp(dconv_w, j, isf);
      else if ((j -= 196608) < 65536) v = ldp(c1_w, j, isf);
      else if ((j -= 65536) < 16384)  v = ldp(r0_w1, j, isf);
      else if ((j -= 16384) < 16384)  v = ldp(r0_w2, j, isf);
      else { j -= 16384;              v = ldp(fin_w, j, isf); }
      wbuf[i] = (f16)v;
    } else {
      int j = i - W_F16TOT; float v;
      if (j < 128)               v = ldp(map_b, j, isf);
      else if ((j -= 128) < 512) v = ldp(dconv_b, j, isf);
      else if ((j -= 512) < 512) v = ldp(c1_b, j, isf);
      else if ((j -= 512) < 128) v = ldp(r0_b1, j, isf);
      else if ((j -= 128) < 128) v = ldp(r0_b2, j, isf);
      else if ((j -= 128) < 64)  v = ldp(fin_b, j, isf);
      else if ((j -= 64) < 64)   v = ldp(prelu_w, j, isf);
      else { j -= 64;            v = ldp(map_w, j, isf); }
      fsec[i - W_F16TOT] = v;
    }
  }
}

// Ping-pong MFMA GEMM phase, 8-wave decomposition: 4 cell-groups (cg) x 2 ng.
// Each wave: 4 M-tiles (16 mt slots, 15 used) x 64 out-ch. 512-thread block
// = 2 waves/SIMD -> 256 regs/wave budget: acc[4][4]=64 + Wf 16 + Af 16 +
// facc 32 + addressing ~60 fits with ZERO SPILLS -> scratch ~0 -> per-XCD L2
// stays clean -> W loads L2/L1-resident. Rolled t/kb. pk[mi] = 3x8-bit rows.
// MODE 0: D = silu(acc+b). MODE 1: D = silu(acc+b) + D_old (disjoint RMW).
template<int NTAPS, int MODE>
__device__ __forceinline__ void phase(
    const f16* __restrict__ S, f16* __restrict__ D,
    const f16* __restrict__ W, const float* __restrict__ bp,
    const unsigned (&pk)[4], int tid)
{
  const int lane = tid & 63;
  const int lrow = lane & 15;
  const int qb   = lane & 48;                      // quad*16 (bytes)
  const int wave = tid >> 6;
  const int cg = wave >> 1, ng = wave & 1;         // cg 0..3, ng 0..1
  const int ch0  = ng*64 + (qb >> 2);              // ng*64 + quad*4
  const int wrow = (ng*64 + lrow)*128 + (qb >> 1); // + quad*8 (halves)

  f32x4 acc[4][4];
#pragma unroll
  for (int mi = 0; mi < 4; ++mi)
#pragma unroll
    for (int nt = 0; nt < 4; ++nt) { f32x4 z = {0.f,0.f,0.f,0.f}; acc[mi][nt] = z; }

#pragma unroll
  for (int t = 0; t < NTAPS; ++t) {
    const int tt = (NTAPS == 3) ? t : 1;
    const f16* Wt = W + ((NTAPS == 3) ? t*16384 : 0) + wrow;
#pragma clang loop unroll(disable)
    for (int kb = 0; kb < 4; ++kb) {
      f16x8 Wf0 = *(const f16x8*)(Wt + kb*32);
      f16x8 Wf1 = *(const f16x8*)(Wt + 2048 + kb*32);
      f16x8 Wf2 = *(const f16x8*)(Wt + 4096 + kb*32);
      f16x8 Wf3 = *(const f16x8*)(Wt + 6144 + kb*32);
      f16x8 Af[4];
#pragma unroll
      for (int mi = 0; mi < 4; ++mi) {
        const int pc = (pk[mi] >> (8*tt)) & 255u;  // clamped source row
        Af[mi] = *(const f16x8*)((const char*)S + pc*(AST*2) + qb + kb*64);
      }
#pragma unroll
      for (int mi = 0; mi < 4; ++mi) {
        acc[mi][0] = MFMA16(Wf0, Af[mi], acc[mi][0]);
        acc[mi][1] = MFMA16(Wf1, Af[mi], acc[mi][1]);
        acc[mi][2] = MFMA16(Wf2, Af[mi], acc[mi][2]);
        acc[mi][3] = MFMA16(Wf3, Af[mi], acc[mi][3]);
      }
    }
  }

  f32x4 bb[4];
#pragma unroll
  for (int nt = 0; nt < 4; ++nt) bb[nt] = *(const f32x4*)(bp + ch0 + nt*16);
#pragma unroll
  for (int mi = 0; mi < 4; ++mi) {
    const int cell = (cg*4 + mi)*16 + lrow;
    const int row  = (cell < NCELL) ? cell : 226;  // dump row for invalid
#pragma unroll
    for (int nt = 0; nt < 4; ++nt) {
      f16* dp = D + row*AST + ch0 + nt*16;
      float v0 = silu_f(acc[mi][nt][0] + bb[nt][0]);
      float v1 = silu_f(acc[mi][nt][1] + bb[nt][1]);
      float v2 = silu_f(acc[mi][nt][2] + bb[nt][2]);
      float v3 = silu_f(acc[mi][nt][3] + bb[nt][3]);
      if (MODE == 1) {
        f16x4 r = *(const f16x4*)dp;
        v0 += (float)r[0]; v1 += (float)r[1]; v2 += (float)r[2]; v3 += (float)r[3];
      }
      f16x4 o = { (f16)v0, (f16)v1, (f16)v2, (f16)v3 };
      *(f16x4*)dp = o;
    }
  }
  __syncthreads();
}

__global__ __attribute__((amdgpu_flat_work_group_size(NT, NT), amdgpu_waves_per_eu(2, 2)))
void k_all(
    const void* __restrict__ x,
    const void* __restrict__ pdw_w,  const void* __restrict__ pdw_b,
    const void* __restrict__ ppw_w,
    const void* __restrict__ vl1_w,  const void* __restrict__ vl1_b,
    const void* __restrict__ vl2_w,  const void* __restrict__ vl2_b,
    const void* __restrict__ vlf_w,  const void* __restrict__ vlf_b,
    const void* __restrict__ pscale, const void* __restrict__ vscale,
    const f16* __restrict__ wbuf, float* __restrict__ out, int badflag)
{
  extern __shared__ __align__(16) char dyn[];
  f16* bufA = (f16*)dyn;                 // NROW*AST halves
  f16* bufB = bufA + NROW*AST;
  __shared__ float xin[452];             // plane0[0..224], 0, plane1[226..450], 0
  __shared__ float vred[NT];
  __shared__ float vvA[32], vvB[32];
  __shared__ int sflag;

  const int b = blockIdx.x, tid = threadIdx.x;
  const int lane = tid & 63, wave = tid >> 6;
  const int cg = wave >> 1, ng = wave & 1;      // 4 cell-groups x 2 ch-groups
  const int lrow = lane & 15;
  const float* fsec = (const float*)(wbuf + W_F16TOT);

  if (tid < 64) {
    unsigned v = ((const u16*)x)[2*tid];
    unsigned long long m = __ballot(v > 0x4000u);
    if (tid == 0) sflag = (__popcll(m) > 16) ? 1 : 0;
  }
  // zero-pad row 225 of both ping-pong buffers (never written afterwards)
  for (int i = tid; i < AST; i += NT) {
    bufA[225*AST + i] = (f16)0.f;
    bufB[225*AST + i] = (f16)0.f;
  }
  __syncthreads();
  const int isf = sflag;

  for (int i = tid; i < 452; i += NT) {
    float v;
    if (i < 225)       v = ldp(x, (size_t)b*450 + i, isf);
    else if (i == 225) v = 0.f;
    else if (i < 451)  v = ldp(x, (size_t)b*450 + 225 + (i - 226), isf);
    else               v = 0.f;
    xin[i] = v;
  }

  float facc[4][2][4];     // fin accumulator: [mi][nt][j], ch = ng*32+nt*16+quad*4+j
#pragma unroll
  for (int mi = 0; mi < 4; ++mi)
#pragma unroll
    for (int nt = 0; nt < 2; ++nt)
#pragma unroll
      for (int j = 0; j < 4; ++j) facc[mi][nt][j] = 0.f;

  __syncthreads();   // xin + zero rows ready

#pragma clang loop unroll(disable)
  for (int d = 0; d < 4; ++d) {
    const int dr = (d == 0) ? 0 : ((d == 3) ? -1 : 1);
    const int dc = (d == 1) ? 0 : 1;

    // per-direction: clamped source cell per (mi, tap), packed 8-bit x3 into pk[mi]
    unsigned pk[4];
#pragma unroll
    for (int mi = 0; mi < 4; ++mi) {
      const int cell = (cg*4 + mi)*16 + lrow;
      const bool v0 = cell < NCELL;
      const int r = cell/15, c = cell - (cell/15)*15;
      unsigned p = 0;
#pragma unroll
      for (int t = 0; t < 3; ++t) {
        const int rs = r + (t-1)*dr, cs = c + (t-1)*dc;
        const bool v = v0 & (rs >= 0) & (rs < 15) & (cs >= 0) & (cs < 15);
        p |= (unsigned)(v ? rs*15 + cs : 225) << (8*t);
      }
      pk[mi] = p;
    }

    // ---- map conv (K=2, 3 taps) + silu -> bufA ----
    {
      const int qb = lane & 48;
      const int ch0 = ng*64 + (qb >> 2);
#pragma unroll
      for (int nt = 0; nt < 4; ++nt) {
        const int chn = ch0 + nt*16;
        f32x4 mb = *(const f32x4*)(fsec + F_MAPB + chn);
        f32x4 wt[3][2];
#pragma unroll
        for (int t = 0; t < 3; ++t) {
          wt[t][0] = *(const f32x4*)(fsec + F_MAPW + (t*128 + chn)*2);
          wt[t][1] = *(const f32x4*)(fsec + F_MAPW + (t*128 + chn)*2 + 4);
        }
#pragma unroll
        for (int mi = 0; mi < 4; ++mi) {
          const int cell = (cg*4 + mi)*16 + lrow;
          const int row  = (cell < NCELL) ? cell : 226;
          f16x4 o;
#pragma unroll
          for (int j = 0; j < 4; ++j) {
            float s = mb[j];
#pragma unroll
            for (int t = 0; t < 3; ++t) {
              const int sp = (pk[mi] >> (8*t)) & 255u;
              s += wt[t][j>>1][(j&1)*2]*xin[sp] + wt[t][j>>1][(j&1)*2+1]*xin[226 + sp];
            }
            o[j] = (f16)silu_f(s);
          }
          *(f16x4*)(bufA + row*AST + chn) = o;
        }
      }
    }
    __syncthreads();

#pragma clang loop unroll(disable)
    for (int l = 0; l < 4; ++l) {
      phase<3, 0>(bufA, bufB, wbuf + W_DCONV + (size_t)l*49152,
                  fsec + F_DCONVB + l*128, pk, tid);
      phase<1, 1>(bufB, bufA, wbuf + W_C1 + (size_t)l*16384,
                  fsec + F_C1B + l*128, pk, tid);
    }
    phase<1, 0>(bufA, bufB, wbuf + W_R01, fsec + F_R0B1, pk, tid);
    phase<1, 1>(bufB, bufA, wbuf + W_R02, fsec + F_R0B2, pk, tid);

    // ---- fin: 64 out-ch (ng*32 + nt*16 per wave), reads bufA only ----
    {
      const int qb = lane & 48;
      f32x4 fa[4][2];
#pragma unroll
      for (int mi = 0; mi < 4; ++mi) {
        f32x4 z = {0.f,0.f,0.f,0.f};
        fa[mi][0] = z; fa[mi][1] = z;
      }
      const f16* Wt = wbuf + W_FIN + (ng*32 + lrow)*128 + (qb >> 1);
#pragma clang loop unroll(disable)
      for (int kb = 0; kb < 4; ++kb) {
        f16x8 Wf0 = *(const f16x8*)(Wt + kb*32);
        f16x8 Wf1 = *(const f16x8*)(Wt + 2048 + kb*32);
#pragma unroll
        for (int mi = 0; mi < 4; ++mi) {
          const int pc = (pk[mi] >> 8) & 255u;     // center tap
          f16x8 a = *(const f16x8*)((const char*)bufA + pc*(AST*2) + qb + kb*64);
          fa[mi][0] = MFMA16(Wf0, a, fa[mi][0]);
          fa[mi][1] = MFMA16(Wf1, a, fa[mi][1]);
        }
      }
      const int chf = ng*32 + (qb >> 2);
      f32x4 fb0 = *(const f32x4*)(fsec + F_FINB + chf);
      f32x4 fb1 = *(const f32x4*)(fsec + F_FINB + chf + 16);
#pragma unroll
      for (int mi = 0; mi < 4; ++mi)
#pragma unroll
        for (int j = 0; j < 4; ++j) {
          facc[mi][0][j] += tanh_f((fa[mi][0][j] + fb0[j]) * (1.f/MAXF)) * MAXF;
          facc[mi][1][j] += tanh_f((fa[mi][1][j] + fb1[j]) * (1.f/MAXF)) * MAXF;
        }
    }
    __syncthreads();   // fin reads of bufA done before next map writes
  }

  float* featf = (float*)bufA;   // 226 rows x 64 f32 = 57,856 B (fits region)
  {
    const int qb = lane & 48;
    const int chf = ng*32 + (qb >> 2);
    f32x4 aw0 = *(const f32x4*)(fsec + F_PRELU + chf);
    f32x4 aw1 = *(const f32x4*)(fsec + F_PRELU + chf + 16);
#pragma unroll
    for (int mi = 0; mi < 4; ++mi) {
      const int cell = (cg*4 + mi)*16 + lrow;
      const int fcl  = (cell < NCELL) ? cell : 225;
      f32x4 o0, o1;
#pragma unroll
      for (int j = 0; j < 4; ++j) {
        float s0 = facc[mi][0][j];
        s0 = (s0 >= 0.f) ? s0 : aw0[j]*s0;
        o0[j] = s0 * 0.25f;
        float s1 = facc[mi][1][j];
        s1 = (s1 >= 0.f) ? s1 : aw1[j]*s1;
        o1[j] = s1 * 0.25f;
      }
      *(f32x4*)(featf + fcl*64 + chf) = o0;
      *(f32x4*)(featf + fcl*64 + chf + 16) = o1;
    }
  }
  __syncthreads();

  // ---- value head: mean over cells of ch 32..63 (16 strips x 32 ch) ----
  {
    const int ch = tid & 31, strip = tid >> 5;   // strip 0..15
    float s = 0.f;
    for (int cell = strip; cell < NCELL; cell += 16)
      s += featf[cell*64 + 32 + ch];
    vred[tid] = s;
  }
  __syncthreads();
  if (tid < 32) {
    float s = 0.f;
#pragma unroll
    for (int k = 0; k < 16; ++k) s += vred[k*32 + tid];
    vvA[tid] = fmaxf(s * (1.f/225.f), 0.f);
  }
  __syncthreads();
  if (tid < 32) {
    float s = ldp(vl1_b, tid, isf);
    for (int c2 = 0; c2 < 32; ++c2) s += ldp(vl1_w, tid*32 + c2, isf) * vvA[c2];
    vvB[tid] = fminf(fmaxf(s, 0.f), MAXM);
  }
  __syncthreads();
  if (tid < 32) {
    float s = ldp(vl2_b, tid, isf);
    for (int c2 = 0; c2 < 32; ++c2) s += ldp(vl2_w, tid*32 + c2, isf) * vvB[c2];
    vvA[tid] = fminf(fmaxf(s, 0.f), MAXM);
  }
  __syncthreads();
  if (tid < 3) {
    float s = ldp(vlf_b, tid, isf);
    for (int c2 = 0; c2 < 32; ++c2) s += ldp(vlf_w, tid*32 + c2, isf) * vvA[c2];
    out[b*3 + tid] = s * ldp(vscale, 0, isf);
  }
  __syncthreads();   // value reads of featf[ch32..63] done

  // ---- policy head: depthwise 3x3 on ch 0..31 -> featf[cell][32+ch] ----
  {
    const int ch = tid & 31;           // invariant across grid-stride iters
    float pw[9];
#pragma unroll
    for (int k = 0; k < 9; ++k) pw[k] = ldp(pdw_w, (size_t)ch*9 + k, isf);
    const float pb = ldp(pdw_b, ch, isf);
    for (int i = tid; i < NCELL*32; i += NT) {
      const int cell = i >> 5;
      const int r = cell/15, c = cell - r*15;
      float s = pb;
#pragma unroll
      for (int kr = 0; kr < 3; ++kr)
#pragma unroll
        for (int kc = 0; kc < 3; ++kc) {
          const int rr = r + kr - 1, cc = c + kc - 1;
          if (rr >= 0 && rr < 15 && cc >= 0 && cc < 15)
            s += pw[kr*3 + kc] * featf[(rr*15 + cc)*64 + ch];
        }
      s = (s >= 0.f) ? s : s * (1.f/16.f);
      s = fminf(fmaxf(s, -MAXF), MAXF);
      featf[cell*64 + 32 + ch] = s;
    }
  }
  __syncthreads();

  const float psc = ldp(pscale, 0, isf);
  for (int cell = tid; cell < NCELL; cell += NT) {
    float s = 0.f;
#pragma unroll
    for (int c2 = 0; c2 < 32; ++c2)
      s += ldp(ppw_w, c2, isf) * featf[cell*64 + 32 + c2];
    s = (s >= 0.f) ? s : s * (1.f/16.f);
    out[1536 + b*NCELL + cell] = s * psc;
  }

  if (badflag && b == 0 && tid == 0) out[0] = 100000.f;
}

extern "C" void kernel_launch(void* const* d_in, const int* in_sizes, int n_in,
                              void* d_out, int out_size, void* d_ws, size_t ws_size,
                              hipStream_t stream)
{
  static const int EXP[25] = {230400, 768, 128, 196608, 512, 65536, 512,
                              16384, 128, 16384, 128, 8192, 64, 64,
                              288, 32, 32, 1024, 32, 1024, 32, 96, 3, 1, 1};
  int bad = (n_in != 25) ? 1 : 0;
  if (!bad) for (int i = 0; i < 25; ++i) if (in_sizes[i] != EXP[i]) bad = 1;
  if (out_size != 116736) bad = 1;

  if (hipFuncSetAttribute(reinterpret_cast<const void*>(k_all),
                          hipFuncAttributeMaxDynamicSharedMemorySize,
                          DYN_LDS) != hipSuccess) bad = 1;

  f16* wbuf = (f16*)d_ws;

  k_prep<<<512, 256, 0, stream>>>(d_in[3], d_in[5], d_in[7], d_in[9], d_in[11],
                                  d_in[1], d_in[2], d_in[4], d_in[6], d_in[8],
                                  d_in[10], d_in[12], d_in[13], d_in[0], wbuf);

  k_all<<<512, NT, DYN_LDS, stream>>>(
      d_in[0], d_in[14], d_in[15], d_in[16],
      d_in[17], d_in[18], d_in[19], d_in[20], d_in[21], d_in[22],
      d_in[23], d_in[24], wbuf, (float*)d_out, bad);
}

// Round 14
// 798.213 us; speedup vs baseline: 1.1763x; 1.1763x over previous
//
#include <hip/hip_runtime.h>
#include <math.h>

typedef unsigned short u16;
typedef _Float16 f16;
typedef __attribute__((ext_vector_type(4))) _Float16 f16x4;
typedef __attribute__((ext_vector_type(8))) _Float16 f16x8;
typedef __attribute__((ext_vector_type(4))) float f32x4;

#define NCELL 225
#define AST   136              // act stride in halves (272 B)
#define NROW  227              // 225 cells + zero row (225) + dump row (226)
#define MAXF  31.75f
#define MAXM  (127.0f/((4.0f/16.0f)*3600.0f/256.0f))
#define DYN_LDS (2*NROW*AST*2) // 123,488 B: bufA | bufB (ping-pong, 1 blk/CU)
#define NT    768              // 12 waves = 3 waves/SIMD (measured optimum)

// f16 weight buffer layout (element offsets)
#define W_DCONV 0
#define W_C1    196608
#define W_R01   262144
#define W_R02   278528
#define W_FIN   294912
#define W_F16TOT 303104
// f32 section (float-element offsets from wbuf + W_F16TOT)
#define F_MAPB   0
#define F_DCONVB 128
#define F_C1B    640
#define F_R0B1   1152
#define F_R0B2   1280
#define F_FINB   1408
#define F_PRELU  1472
#define F_MAPW   1536
#define F_TOT    2304

__device__ __forceinline__ float bfu(unsigned h){ union{unsigned i; float f;} v; v.i=h<<16; return v.f; }
__device__ __forceinline__ float rcp_f(float x){ return __builtin_amdgcn_rcpf(x); }
__device__ __forceinline__ float silu_f(float x){ return x*rcp_f(1.f+__expf(-x)); }
__device__ __forceinline__ float tanh_f(float z){ return 1.f - 2.f*rcp_f(__expf(2.f*z)+1.f); }
__device__ __forceinline__ float ldp(const void* p, size_t i, int isf){
  return isf ? ((const float*)p)[i] : bfu(((const u16*)p)[i]);
}
#define MFMA16(A, B, C) __builtin_amdgcn_mfma_f32_16x16x32_f16((A), (B), (C), 0, 0, 0)

__global__ __launch_bounds__(256) void k_prep(
    const void* __restrict__ dconv_w, const void* __restrict__ c1_w,
    const void* __restrict__ r0_w1,  const void* __restrict__ r0_w2,
    const void* __restrict__ fin_w,  const void* __restrict__ map_w,
    const void* __restrict__ map_b,  const void* __restrict__ dconv_b,
    const void* __restrict__ c1_b,   const void* __restrict__ r0_b1,
    const void* __restrict__ r0_b2,  const void* __restrict__ fin_b,
    const void* __restrict__ prelu_w,
    const void* __restrict__ x, f16* __restrict__ wbuf)
{
  __shared__ int sflag;
  if (threadIdx.x < 64) {
    unsigned v = ((const u16*)x)[2*threadIdx.x];
    unsigned long long m = __ballot(v > 0x4000u);
    if (threadIdx.x == 0) sflag = (__popcll(m) > 16) ? 1 : 0;
  }
  __syncthreads();
  const int isf = sflag;
  float* fsec = (float*)(wbuf + W_F16TOT);
  const int NTOT = W_F16TOT + F_TOT;
  for (int i = blockIdx.x*256 + threadIdx.x; i < NTOT; i += gridDim.x*256) {
    if (i < W_F16TOT) {
      float v; int j = i;
      if (j < 196608)                 v = ldp(dconv_w, j, isf);
      else if ((j -= 196608) < 65536) v = ldp(c1_w, j, isf);
      else if ((j -= 65536) < 16384)  v = ldp(r0_w1, j, isf);
      else if ((j -= 16384) < 16384)  v = ldp(r0_w2, j, isf);
      else { j -= 16384;              v = ldp(fin_w, j, isf); }
      wbuf[i] = (f16)v;
    } else {
      int j = i - W_F16TOT; float v;
      if (j < 128)               v = ldp(map_b, j, isf);
      else if ((j -= 128) < 512) v = ldp(dconv_b, j, isf);
      else if ((j -= 512) < 512) v = ldp(c1_b, j, isf);
      else if ((j -= 512) < 128) v = ldp(r0_b1, j, isf);
      else if ((j -= 128) < 128) v = ldp(r0_b2, j, isf);
      else if ((j -= 128) < 64)  v = ldp(fin_b, j, isf);
      else if ((j -= 64) < 64)   v = ldp(prelu_w, j, isf);
      else { j -= 64;            v = ldp(map_w, j, isf); }
      fsec[i - W_F16TOT] = v;
    }
  }
}

// Ping-pong MFMA GEMM phase, 12-wave decomposition: 3 cell-groups (cg) x 4 ng.
// Each wave: 5 M-tiles (15 mt total = exactly 225 cells) x 32 out-ch.
// 768-thread block = 3 waves/SIMD (measured optimum of the occupancy-register
// curve: 47%/64r=935, 35%/84r=777, 24%/128r=903 µs).
// t-loop ROLLED (this round's single change vs R12): the t x3 unroll kept 3 taps
// of W-pointers + A-addresses transiently live — the suspected source of the
// residual 140 MB spill traffic at VGPR=84.
// pk[mi] = 3x8-bit clamped source rows. MODE 0: D = silu(acc+b).
// MODE 1: D = silu(acc+b) + D_old (disjoint-owner RMW on D). One barrier/phase.
template<int NTAPS, int MODE>
__device__ __forceinline__ void phase(
    const f16* __restrict__ S, f16* __restrict__ D,
    const f16* __restrict__ W, const float* __restrict__ bp,
    const unsigned (&pk)[5], int tid)
{
  const int lane = tid & 63;
  const int lrow = lane & 15;
  const int qb   = lane & 48;                      // quad*16 (bytes)
  const int wave = tid >> 6;
  const int cg = wave >> 2, ng = wave & 3;         // cg 0..2, ng 0..3
  const int ch0  = ng*32 + (qb >> 2);              // ng*32 + quad*4
  const int wrow = (ng*32 + lrow)*128 + (qb >> 1); // + quad*8 (halves)

  f32x4 acc[5][2];
#pragma unroll
  for (int mi = 0; mi < 5; ++mi) {
    f32x4 z = {0.f,0.f,0.f,0.f};
    acc[mi][0] = z; acc[mi][1] = z;
  }
#pragma clang loop unroll(disable)
  for (int t = 0; t < NTAPS; ++t) {
    const int tt = (NTAPS == 3) ? t : 1;
    const f16* Wt = W + ((NTAPS == 3) ? t*16384 : 0) + wrow;
#pragma clang loop unroll(disable)
    for (int kb = 0; kb < 4; ++kb) {
      f16x8 Wf0 = *(const f16x8*)(Wt + kb*32);
      f16x8 Wf1 = *(const f16x8*)(Wt + 2048 + kb*32);
      f16x8 Af[5];
#pragma unroll
      for (int mi = 0; mi < 5; ++mi) {
        const int pc = (pk[mi] >> (8*tt)) & 255u;  // clamped source row
        Af[mi] = *(const f16x8*)((const char*)S + pc*(AST*2) + qb + kb*64);
      }
#pragma unroll
      for (int mi = 0; mi < 5; ++mi) {
        acc[mi][0] = MFMA16(Wf0, Af[mi], acc[mi][0]);
        acc[mi][1] = MFMA16(Wf1, Af[mi], acc[mi][1]);
      }
    }
  }
  f32x4 bb0 = *(const f32x4*)(bp + ch0);
  f32x4 bb1 = *(const f32x4*)(bp + ch0 + 16);
#pragma unroll
  for (int mi = 0; mi < 5; ++mi) {
    const int cell = (cg*5 + mi)*16 + lrow;
    const int row  = (cell < NCELL) ? cell : 226;  // dump row for invalid
#pragma unroll
    for (int nt = 0; nt < 2; ++nt) {
      f16* dp = D + row*AST + ch0 + nt*16;
      const f32x4 bb = nt ? bb1 : bb0;
      float v0 = silu_f(acc[mi][nt][0] + bb[0]);
      float v1 = silu_f(acc[mi][nt][1] + bb[1]);
      float v2 = silu_f(acc[mi][nt][2] + bb[2]);
      float v3 = silu_f(acc[mi][nt][3] + bb[3]);
      if (MODE == 1) {
        f16x4 r = *(const f16x4*)dp;
        v0 += (float)r[0]; v1 += (float)r[1]; v2 += (float)r[2]; v3 += (float)r[3];
      }
      f16x4 o = { (f16)v0, (f16)v1, (f16)v2, (f16)v3 };
      *(f16x4*)dp = o;
    }
  }
  __syncthreads();
}

__global__ __attribute__((amdgpu_flat_work_group_size(NT, NT), amdgpu_waves_per_eu(3, 3)))
void k_all(
    const void* __restrict__ x,
    const void* __restrict__ pdw_w,  const void* __restrict__ pdw_b,
    const void* __restrict__ ppw_w,
    const void* __restrict__ vl1_w,  const void* __restrict__ vl1_b,
    const void* __restrict__ vl2_w,  const void* __restrict__ vl2_b,
    const void* __restrict__ vlf_w,  const void* __restrict__ vlf_b,
    const void* __restrict__ pscale, const void* __restrict__ vscale,
    const f16* __restrict__ wbuf, float* __restrict__ out, int badflag)
{
  extern __shared__ __align__(16) char dyn[];
  f16* bufA = (f16*)dyn;                 // NROW*AST halves
  f16* bufB = bufA + NROW*AST;
  __shared__ float xin[452];             // plane0[0..224], 0, plane1[226..450], 0
  __shared__ float vred[NT];
  __shared__ float vvA[32], vvB[32];
  __shared__ int sflag;

  const int b = blockIdx.x, tid = threadIdx.x;
  const int lane = tid & 63, wave = tid >> 6;
  const int cg = wave >> 2, ng = wave & 3;      // 3 cell-groups x 4 ch-groups
  const int lrow = lane & 15;
  const float* fsec = (const float*)(wbuf + W_F16TOT);

  if (tid < 64) {
    unsigned v = ((const u16*)x)[2*tid];
    unsigned long long m = __ballot(v > 0x4000u);
    if (tid == 0) sflag = (__popcll(m) > 16) ? 1 : 0;
  }
  // zero-pad row 225 of both ping-pong buffers (never written afterwards)
  for (int i = tid; i < AST; i += NT) {
    bufA[225*AST + i] = (f16)0.f;
    bufB[225*AST + i] = (f16)0.f;
  }
  __syncthreads();
  const int isf = sflag;

  for (int i = tid; i < 452; i += NT) {
    float v;
    if (i < 225)       v = ldp(x, (size_t)b*450 + i, isf);
    else if (i == 225) v = 0.f;
    else if (i < 451)  v = ldp(x, (size_t)b*450 + 225 + (i - 226), isf);
    else               v = 0.f;
    xin[i] = v;
  }

  float facc[5][2][2];     // fin accumulator: [mi][jp][h], ch = ng*16 + quad*4 ...
#pragma unroll
  for (int mi = 0; mi < 5; ++mi)
#pragma unroll
    for (int jp = 0; jp < 2; ++jp) { facc[mi][jp][0] = 0.f; facc[mi][jp][1] = 0.f; }

  __syncthreads();   // xin + zero rows ready

#pragma clang loop unroll(disable)
  for (int d = 0; d < 4; ++d) {
    const int dr = (d == 0) ? 0 : ((d == 3) ? -1 : 1);
    const int dc = (d == 1) ? 0 : 1;

    // per-direction: clamped source cell per (mi, tap), packed 8-bit x3 into pk[mi]
    unsigned pk[5];
#pragma unroll
    for (int mi = 0; mi < 5; ++mi) {
      const int cell = (cg*5 + mi)*16 + lrow;
      const bool v0 = cell < NCELL;
      const int r = cell/15, c = cell - (cell/15)*15;
      unsigned p = 0;
#pragma unroll
      for (int t = 0; t < 3; ++t) {
        const int rs = r + (t-1)*dr, cs = c + (t-1)*dc;
        const bool v = v0 & (rs >= 0) & (rs < 15) & (cs >= 0) & (cs < 15);
        p |= (unsigned)(v ? rs*15 + cs : 225) << (8*t);
      }
      pk[mi] = p;
    }

    // ---- map conv (K=2, 3 taps) + silu -> bufA ----
    {
      const int qb = lane & 48;
      const int ch0 = ng*32 + (qb >> 2);
#pragma unroll
      for (int nt = 0; nt < 2; ++nt) {
        const int chn = ch0 + nt*16;
        f32x4 mb = *(const f32x4*)(fsec + F_MAPB + chn);
        f32x4 wt[3][2];
#pragma unroll
        for (int t = 0; t < 3; ++t) {
          wt[t][0] = *(const f32x4*)(fsec + F_MAPW + (t*128 + chn)*2);
          wt[t][1] = *(const f32x4*)(fsec + F_MAPW + (t*128 + chn)*2 + 4);
        }
#pragma unroll
        for (int mi = 0; mi < 5; ++mi) {
          const int cell = (cg*5 + mi)*16 + lrow;
          const int row  = (cell < NCELL) ? cell : 226;
          f16x4 o;
#pragma unroll
          for (int j = 0; j < 4; ++j) {
            float s = mb[j];
#pragma unroll
            for (int t = 0; t < 3; ++t) {
              const int sp = (pk[mi] >> (8*t)) & 255u;
              s += wt[t][j>>1][(j&1)*2]*xin[sp] + wt[t][j>>1][(j&1)*2+1]*xin[226 + sp];
            }
            o[j] = (f16)silu_f(s);
          }
          *(f16x4*)(bufA + row*AST + chn) = o;
        }
      }
    }
    __syncthreads();

#pragma clang loop unroll(disable)
    for (int l = 0; l < 4; ++l) {
      phase<3, 0>(bufA, bufB, wbuf + W_DCONV + (size_t)l*49152,
                  fsec + F_DCONVB + l*128, pk, tid);
      phase<1, 1>(bufB, bufA, wbuf + W_C1 + (size_t)l*16384,
                  fsec + F_C1B + l*128, pk, tid);
    }
    phase<1, 0>(bufA, bufB, wbuf + W_R01, fsec + F_R0B1, pk, tid);
    phase<1, 1>(bufB, bufA, wbuf + W_R02, fsec + F_R0B2, pk, tid);

    // ---- fin: 64 out-ch (ng*16 per wave), tanh-clamp accumulate (reads bufA) ----
    {
      const int qb = lane & 48;
      f32x4 fa[5];
#pragma unroll
      for (int mi = 0; mi < 5; ++mi) { f32x4 z = {0.f,0.f,0.f,0.f}; fa[mi] = z; }
      const f16* Wt = wbuf + W_FIN + (ng*16 + lrow)*128 + (qb >> 1);
#pragma clang loop unroll(disable)
      for (int kb = 0; kb < 4; ++kb) {
        f16x8 Wf = *(const f16x8*)(Wt + kb*32);
#pragma unroll
        for (int mi = 0; mi < 5; ++mi) {
          const int pc = (pk[mi] >> 8) & 255u;     // center tap
          f16x8 a = *(const f16x8*)((const char*)bufA + pc*(AST*2) + qb + kb*64);
          fa[mi] = MFMA16(Wf, a, fa[mi]);
        }
      }
      const int chf = ng*16 + (qb >> 2);
      f32x4 fb = *(const f32x4*)(fsec + F_FINB + chf);
#pragma unroll
      for (int mi = 0; mi < 5; ++mi)
#pragma unroll
        for (int j = 0; j < 4; ++j)
          facc[mi][j>>1][j&1] += tanh_f((fa[mi][j] + fb[j]) * (1.f/MAXF)) * MAXF;
    }
    __syncthreads();   // fin reads of bufA done before next map writes
  }

  float* featf = (float*)bufA;   // 226 rows x 64 f32 = 57,856 B (fits region)
  {
    const int qb = lane & 48;
    const int chf = ng*16 + (qb >> 2);
    f32x4 aw = *(const f32x4*)(fsec + F_PRELU + chf);
#pragma unroll
    for (int mi = 0; mi < 5; ++mi) {
      const int cell = (cg*5 + mi)*16 + lrow;
      const int fcl  = (cell < NCELL) ? cell : 225;
      f32x4 o;
#pragma unroll
      for (int j = 0; j < 4; ++j) {
        float s = facc[mi][j>>1][j&1];
        s = (s >= 0.f) ? s : aw[j]*s;
        o[j] = s * 0.25f;
      }
      *(f32x4*)(featf + fcl*64 + chf) = o;
    }
  }
  __syncthreads();

  // ---- value head: mean over cells of ch 32..63 (24 strips x 32 ch) ----
  {
    const int ch = tid & 31, strip = tid >> 5;   // strip 0..23
    float s = 0.f;
    for (int cell = strip; cell < NCELL; cell += 24)
      s += featf[cell*64 + 32 + ch];
    vred[tid] = s;
  }
  __syncthreads();
  if (tid < 32) {
    float s = 0.f;
#pragma unroll
    for (int k = 0; k < 24; ++k) s += vred[k*32 + tid];
    vvA[tid] = fmaxf(s * (1.f/225.f), 0.f);
  }
  __syncthreads();
  if (tid < 32) {
    float s = ldp(vl1_b, tid, isf);
    for (int c2 = 0; c2 < 32; ++c2) s += ldp(vl1_w, tid*32 + c2, isf) * vvA[c2];
    vvB[tid] = fminf(fmaxf(s, 0.f), MAXM);
  }
  __syncthreads();
  if (tid < 32) {
    float s = ldp(vl2_b, tid, isf);
    for (int c2 = 0; c2 < 32; ++c2) s += ldp(vl2_w, tid*32 + c2, isf) * vvB[c2];
    vvA[tid] = fminf(fmaxf(s, 0.f), MAXM);
  }
  __syncthreads();
  if (tid < 3) {
    float s = ldp(vlf_b, tid, isf);
    for (int c2 = 0; c2 < 32; ++c2) s += ldp(vlf_w, tid*32 + c2, isf) * vvA[c2];
    out[b*3 + tid] = s * ldp(vscale, 0, isf);
  }
  __syncthreads();   // value reads of featf[ch32..63] done

  // ---- policy head: depthwise 3x3 on ch 0..31 -> featf[cell][32+ch] ----
  {
    const int ch = tid & 31;           // invariant across grid-stride iters
    float pw[9];
#pragma unroll
    for (int k = 0; k < 9; ++k) pw[k] = ldp(pdw_w, (size_t)ch*9 + k, isf);
    const float pb = ldp(pdw_b, ch, isf);
    for (int i = tid; i < NCELL*32; i += NT) {
      const int cell = i >> 5;
      const int r = cell/15, c = cell - r*15;
      float s = pb;
#pragma unroll
      for (int kr = 0; kr < 3; ++kr)
#pragma unroll
        for (int kc = 0; kc < 3; ++kc) {
          const int rr = r + kr - 1, cc = c + kc - 1;
          if (rr >= 0 && rr < 15 && cc >= 0 && cc < 15)
            s += pw[kr*3 + kc] * featf[(rr*15 + cc)*64 + ch];
        }
      s = (s >= 0.f) ? s : s * (1.f/16.f);
      s = fminf(fmaxf(s, -MAXF), MAXF);
      featf[cell*64 + 32 + ch] = s;
    }
  }
  __syncthreads();

  const float psc = ldp(pscale, 0, isf);
  for (int cell = tid; cell < NCELL; cell += NT) {
    float s = 0.f;
#pragma unroll
    for (int c2 = 0; c2 < 32; ++c2)
      s += ldp(ppw_w, c2, isf) * featf[cell*64 + 32 + c2];
    s = (s >= 0.f) ? s : s * (1.f/16.f);
    out[1536 + b*NCELL + cell] = s * psc;
  }

  if (badflag && b == 0 && tid == 0) out[0] = 100000.f;
}

extern "C" void kernel_launch(void* const* d_in, const int* in_sizes, int n_in,
                              void* d_out, int out_size, void* d_ws, size_t ws_size,
                              hipStream_t stream)
{
  static const int EXP[25] = {230400, 768, 128, 196608, 512, 65536, 512,
                              16384, 128, 16384, 128, 8192, 64, 64,
                              288, 32, 32, 1024, 32, 1024, 32, 96, 3, 1, 1};
  int bad = (n_in != 25) ? 1 : 0;
  if (!bad) for (int i = 0; i < 25; ++i) if (in_sizes[i] != EXP[i]) bad = 1;
  if (out_size != 116736) bad = 1;

  if (hipFuncSetAttribute(reinterpret_cast<const void*>(k_all),
                          hipFuncAttributeMaxDynamicSharedMemorySize,
                          DYN_LDS) != hipSuccess) bad = 1;

  f16* wbuf = (f16*)d_ws;

  k_prep<<<512, 256, 0, stream>>>(d_in[3], d_in[5], d_in[7], d_in[9], d_in[11],
                                  d_in[1], d_in[2], d_in[4], d_in[6], d_in[8],
                                  d_in[10], d_in[12], d_in[13], d_in[0], wbuf);

  k_all<<<512, NT, DYN_LDS, stream>>>(
      d_in[0], d_in[14], d_in[15], d_in[16],
      d_in[17], d_in[18], d_in[19], d_in[20], d_in[21], d_in[22],
      d_in[23], d_in[24], wbuf, (float*)d_out, bad);
}